// Round 7
// baseline (36.434 us; speedup 1.0000x reference)
//
#include <hip/hip_runtime.h>
#include <stdint.h>

#define NF   2344
#define ACCW 8
#define NA   38
#define TPB  512

__device__ __forceinline__ unsigned short f32_to_bf16(float f) {
    unsigned u = __float_as_uint(f);
    u += 0x7FFFu + ((u >> 16) & 1u);   // round-to-nearest-even
    return (unsigned short)(u >> 16);
}
__device__ __forceinline__ float bf16_lo(unsigned u) { return __uint_as_float(u << 16); }
__device__ __forceinline__ float bf16_hi(unsigned u) { return __uint_as_float(u & 0xFFFF0000u); }

// 1 thread = 1 element. 38 indices per color loaded as 10 int4:
// j=0..8 at byte 16j (ints 0..35), j=9 at byte 136 (ints 34..37, use .z/.w).
// 16B/lane/instr = best L1 line-economy (10 line-events/element/color pair);
// grid = 4096 waves -> 16 waves/CU.
__global__ __launch_bounds__(TPB, 4) void nnue_fwd(
    const int* __restrict__ bfeat, const int* __restrict__ wfeat,
    const int* __restrict__ stm,
    const float* __restrict__ w1, const float* __restrict__ b1,
    const float* __restrict__ w2, const float* __restrict__ b2,
    float* __restrict__ out, int nbatch)
{
    __shared__ unsigned short tbl[NF * ACCW];   // bf16 table, 16B/row (37.9 KB)

    for (int j = threadIdx.x; j < (NF * ACCW) / 4; j += TPB) {
        float4 v = reinterpret_cast<const float4*>(w1)[j];
        unsigned lo = (unsigned)f32_to_bf16(v.x) | ((unsigned)f32_to_bf16(v.y) << 16);
        unsigned hi = (unsigned)f32_to_bf16(v.z) | ((unsigned)f32_to_bf16(v.w) << 16);
        reinterpret_cast<uint2*>(tbl)[j] = make_uint2(lo, hi);
    }
    __syncthreads();

    const int e = blockIdx.x * TPB + threadIdx.x;
    if (e >= nbatch) return;

#define G(acc, idx) { \
        uint4 r = *reinterpret_cast<const uint4*>( \
            reinterpret_cast<const char*>(tbl) + ((unsigned)(idx) << 4)); \
        acc[0] += bf16_lo(r.x); acc[1] += bf16_hi(r.x); \
        acc[2] += bf16_lo(r.y); acc[3] += bf16_hi(r.y); \
        acc[4] += bf16_lo(r.z); acc[5] += bf16_hi(r.z); \
        acc[6] += bf16_lo(r.w); acc[7] += bf16_hi(r.w); }

#define GATHER_COLOR(acc, basep) { \
        const char* cb = reinterpret_cast<const char*>(basep); \
        int4 q[10]; \
        _Pragma("unroll") \
        for (int j = 0; j < 9; ++j) \
            q[j] = *reinterpret_cast<const int4*>(cb + 16 * j); \
        q[9] = *reinterpret_cast<const int4*>(cb + 136); \
        _Pragma("unroll") \
        for (int j = 0; j < 9; ++j) { \
            G(acc, q[j].x); G(acc, q[j].y); G(acc, q[j].z); G(acc, q[j].w); \
        } \
        G(acc, q[9].z); G(acc, q[9].w); }

    float accB[8] = {0,0,0,0,0,0,0,0};
    float accW[8] = {0,0,0,0,0,0,0,0};

    GATHER_COLOR(accB, bfeat + (long)e * NA);
    GATHER_COLOR(accW, wfeat + (long)e * NA);
#undef GATHER_COLOR
#undef G

    // ---- clip + stm-ordered dot (branchless: both halves per color) ----
    float dbl = 0.f, dbh = 0.f, dwl = 0.f, dwh = 0.f;
#pragma unroll
    for (int k = 0; k < 8; ++k) {
        float bv = fminf(fmaxf(accB[k] + b1[k], 0.f), 1.f);
        float wv = fminf(fmaxf(accW[k] + b1[k], 0.f), 1.f);
        dbl += bv * w2[k]; dbh += bv * w2[8 + k];
        dwl += wv * w2[k]; dwh += wv * w2[8 + k];
    }
    const int s = stm[e];
    out[e] = b2[0] + (s == 0 ? (dbl + dwh) : (dbh + dwl));
}

extern "C" void kernel_launch(void* const* d_in, const int* in_sizes, int n_in,
                              void* d_out, int out_size, void* d_ws, size_t ws_size,
                              hipStream_t stream) {
    const int*   bfeat = (const int*)  d_in[0];
    const int*   wfeat = (const int*)  d_in[1];
    const int*   stm   = (const int*)  d_in[2];
    const float* w1    = (const float*)d_in[3];
    const float* b1    = (const float*)d_in[4];
    const float* w2    = (const float*)d_in[5];
    const float* b2    = (const float*)d_in[6];
    float* out = (float*)d_out;

    const int nbatch = in_sizes[2];
    const int grid = (nbatch + TPB - 1) / TPB;
    nnue_fwd<<<grid, TPB, 0, stream>>>(bfeat, wfeat, stm, w1, b1, w2, b2, out, nbatch);
}

// Round 8
// 28.480 us; speedup vs baseline: 1.2793x; 1.2793x over previous
//
#include <hip/hip_runtime.h>
#include <stdint.h>

#define NF   2344
#define ACCW 8
#define NA   38
#define TPB  512

__device__ __forceinline__ unsigned short f32_to_bf16(float f) {
    unsigned u = __float_as_uint(f);
    u += 0x7FFFu + ((u >> 16) & 1u);   // round-to-nearest-even
    return (unsigned short)(u >> 16);
}
__device__ __forceinline__ float bf16_lo(unsigned u) { return __uint_as_float(u << 16); }
__device__ __forceinline__ float bf16_hi(unsigned u) { return __uint_as_float(u & 0xFFFF0000u); }

#define KEEP4(v) asm volatile("" :: "v"(v.x), "v"(v.y), "v"(v.z), "v"(v.w))
#define KEEP2(v) asm volatile("" :: "v"(v.x), "v"(v.y))

// 4 threads per element (q = t&3). Per color, lane q owns ints
// {4q..4q+3} u {16+4q..19+4q} (two int4) and, for q<3, {32+2q,33+2q} (int2):
// exact 38-int cover, quad reads 64B contiguous per instruction.
// All index loads issued up-front (keep-alive asm -> one batched wait).
// Partial acc per lane; quad butterfly (xor 1,2); split-dot epilogue.
__global__ __launch_bounds__(TPB, 4) void nnue_fwd(
    const int* __restrict__ bfeat, const int* __restrict__ wfeat,
    const int* __restrict__ stm,
    const float* __restrict__ w1, const float* __restrict__ b1,
    const float* __restrict__ w2, const float* __restrict__ b2,
    float* __restrict__ out, int nbatch)
{
    __shared__ unsigned short tbl[NF * ACCW];   // bf16 table, 16B/row (37.5 KB)

    for (int j = threadIdx.x; j < (NF * ACCW) / 4; j += TPB) {
        float4 v = reinterpret_cast<const float4*>(w1)[j];
        unsigned lo = (unsigned)f32_to_bf16(v.x) | ((unsigned)f32_to_bf16(v.y) << 16);
        unsigned hi = (unsigned)f32_to_bf16(v.z) | ((unsigned)f32_to_bf16(v.w) << 16);
        reinterpret_cast<uint2*>(tbl)[j] = make_uint2(lo, hi);
    }
    __syncthreads();

    const int t = blockIdx.x * TPB + threadIdx.x;
    const int e = t >> 2;
    const int q = t & 3;
    if (e >= nbatch) return;

    const char* bb = reinterpret_cast<const char*>(bfeat + (long)e * NA);
    const char* wb = reinterpret_cast<const char*>(wfeat + (long)e * NA);

    // ---- issue ALL index loads up front (batched wait via keep-alive) ----
    int4 bA = *reinterpret_cast<const int4*>(bb + 16 * q);
    int4 bB = *reinterpret_cast<const int4*>(bb + 64 + 16 * q);
    int4 wA = *reinterpret_cast<const int4*>(wb + 16 * q);
    int4 wB = *reinterpret_cast<const int4*>(wb + 64 + 16 * q);
    int2 bC = make_int2(0, 0), wC = make_int2(0, 0);
    if (q < 3) {
        bC = *reinterpret_cast<const int2*>(bb + 128 + 8 * q);
        wC = *reinterpret_cast<const int2*>(wb + 128 + 8 * q);
    }
    KEEP4(bA); KEEP4(bB); KEEP4(wA); KEEP4(wB); KEEP2(bC); KEEP2(wC);

#define G(acc, idx) { \
        uint4 r = *reinterpret_cast<const uint4*>( \
            reinterpret_cast<const char*>(tbl) + ((unsigned)(idx) << 4)); \
        acc[0] += bf16_lo(r.x); acc[1] += bf16_hi(r.x); \
        acc[2] += bf16_lo(r.y); acc[3] += bf16_hi(r.y); \
        acc[4] += bf16_lo(r.z); acc[5] += bf16_hi(r.z); \
        acc[6] += bf16_lo(r.w); acc[7] += bf16_hi(r.w); }

    float aB[8] = {0,0,0,0,0,0,0,0};
    float aW[8] = {0,0,0,0,0,0,0,0};

    G(aB, bA.x); G(aB, bA.y); G(aB, bA.z); G(aB, bA.w);
    G(aB, bB.x); G(aB, bB.y); G(aB, bB.z); G(aB, bB.w);
    G(aW, wA.x); G(aW, wA.y); G(aW, wA.z); G(aW, wA.w);
    G(aW, wB.x); G(aW, wB.y); G(aW, wB.z); G(aW, wB.w);
    if (q < 3) {
        G(aB, bC.x); G(aB, bC.y);
        G(aW, wC.x); G(aW, wC.y);
    }
#undef G

    // ---- quad butterfly: all 4 lanes end with full element sums ----
#pragma unroll
    for (int k = 0; k < 8; ++k) {
        aB[k] += __shfl_xor(aB[k], 1); aB[k] += __shfl_xor(aB[k], 2);
        aW[k] += __shfl_xor(aW[k], 1); aW[k] += __shfl_xor(aW[k], 2);
    }

    // ---- split-dot epilogue: lane q computes {dbl,dbh,dwl,dwh}[q] ----
    // q0: clip(B).w2lo  q1: clip(B).w2hi  q2: clip(W).w2lo  q3: clip(W).w2hi
    float d = 0.f;
#pragma unroll
    for (int k = 0; k < 8; ++k) {
        float v = (q < 2) ? aB[k] : aW[k];
        v = fminf(fmaxf(v + b1[k], 0.f), 1.f);
        float wk = (q & 1) ? w2[8 + k] : w2[k];
        d += v * wk;
    }
    const float r    = d + __shfl_xor(d, 3);  // lane0: dbl+dwh, lane1: dbh+dwl
    const float ralt = __shfl_xor(r, 1);      // lane0 gets dbh+dwl
    const int   s    = stm[e];
    if (q == 0) out[e] = b2[0] + (s == 0 ? r : ralt);
}

extern "C" void kernel_launch(void* const* d_in, const int* in_sizes, int n_in,
                              void* d_out, int out_size, void* d_ws, size_t ws_size,
                              hipStream_t stream) {
    const int*   bfeat = (const int*)  d_in[0];
    const int*   wfeat = (const int*)  d_in[1];
    const int*   stm   = (const int*)  d_in[2];
    const float* w1    = (const float*)d_in[3];
    const float* b1    = (const float*)d_in[4];
    const float* w2    = (const float*)d_in[5];
    const float* b2    = (const float*)d_in[6];
    float* out = (float*)d_out;

    const int nbatch = in_sizes[2];
    const long nthread = (long)nbatch * 4;
    const int grid = (int)((nthread + TPB - 1) / TPB);
    nnue_fwd<<<grid, TPB, 0, stream>>>(bfeat, wfeat, stm, w1, b1, w2, b2, out, nbatch);
}